// Round 5
// baseline (322.134 us; speedup 1.0000x reference)
//
#include <hip/hip_runtime.h>
#include <math.h>

// LoE tiled MLP — bf16 MFMA v4: v3 + HW-trig posenc (kills the sincosf spill).
// (Resubmission — round 4 bench never acquired a GPU; no changes vs round 3.)
//
// Block = 16x16 px (256 px). Pixel bit naming: di = d3d2d1d0, dj = e3e2e1e0.
//   ord1 row s1 = [d3 e3 d2 d1 | e2 e1 d0 e0]  (L1 groups = s1>>6, Mtiles = s1>>4)
//   ord2 row s2 = [d2 d1 e2 e1 | d3 e3 d0 e0]  (L2 groups = Mtiles = idx2 = s2>>4)
// Weights pre-packed (pack_w) to bf16 A-role fragments [tile][kt][nt][lane][8];
// h is the B-role operand (lane&15 = pixel), so mfma(w_frag, h_frag) yields
// D^T: lane holds 4 CONSECUTIVE FEATURES (rows) of one pixel (col=lane&15)
// -> epilogue = 2 cvt_pk + 1 ds_write_b64 per fragment; row perms are free.
// Activation rows: 512B, phys = s*512 + ((off + (s&7)*64 + ((s>>3)&1)*32)&511)
// -> b64 writes conflict-free, b128 reads <=2-way.
// Posenc: sin(pi*2^f*x) = v_sin_f32(fract(x*2^(f-1))) — exact exponent scale,
// HW range reduction; 4 VALU/freq-pair, ~6 live regs (was libm sincosf blob).

typedef __attribute__((ext_vector_type(8))) short bf16x8;
typedef __attribute__((ext_vector_type(4))) float f32x4;

#define W0P 0
#define W1P 262144
#define W2P 1310720
#define WLP 2359296

__device__ __forceinline__ unsigned short f2bf(float f){
    unsigned b = __float_as_uint(f);
    return (unsigned short)((b + 0x7FFFu + ((b >> 16) & 1u)) >> 16);
}
__device__ __forceinline__ unsigned cvtpk(float lo, float hi){
    unsigned r;
    asm("v_cvt_pk_bf16_f32 %0, %1, %2" : "=v"(r) : "v"(lo), "v"(hi));
    return r;
}
__device__ __forceinline__ float hwsin(float r){
    float d; asm("v_sin_f32 %0, %1" : "=v"(d) : "v"(r)); return d;
}
__device__ __forceinline__ float hwcos(float r){
    float d; asm("v_cos_f32 %0, %1" : "=v"(d) : "v"(r)); return d;
}
__device__ __forceinline__ float leaky(float v){ return fmaxf(v, 0.2f * v); }
__device__ __forceinline__ int rowaddr(int s, int off){
    return s * 512 + ((off + (s & 7) * 64 + ((s >> 3) & 1) * 32) & 511);
}

// ---------------- weight pack: fp32 -> bf16 A-role fragment layout ----------
__global__ void pack_w(const float* __restrict__ w0, const float* __restrict__ w1,
                       const float* __restrict__ w2, const float* __restrict__ wl,
                       unsigned short* __restrict__ wp)
{
    int tid = blockIdx.x * 256 + threadIdx.x;
    if (tid < 32768) {                       // w0: [16][2][16][64][8], K padded 54->64
        int lane = tid & 63, kt = (tid >> 10) & 1, tile = tid >> 11;
        int n = ((tid >> 6) & 15) * 16 + (lane & 15);
        unsigned short* d = wp + W0P + tid * 8;
#pragma unroll
        for (int r = 0; r < 8; ++r) {
            int k = kt * 32 + (lane >> 4) * 8 + r;
            d[r] = (k < 54) ? f2bf(w0[(tile * 54 + k) * 256 + n]) : (unsigned short)0;
        }
    } else if (tid < 163840) {               // w1: [16][8][16][64][8]
        int idx = tid - 32768;
        int lane = idx & 63, kt = (idx >> 10) & 7, tile = idx >> 13;
        int n = ((idx >> 6) & 15) * 16 + (lane & 15);
        unsigned short* d = wp + W1P + idx * 8;
#pragma unroll
        for (int r = 0; r < 8; ++r)
            d[r] = f2bf(w1[(tile * 256 + kt * 32 + (lane >> 4) * 8 + r) * 256 + n]);
    } else if (tid < 294912) {               // w2: [16][8][16][64][8]
        int idx = tid - 163840;
        int lane = idx & 63, kt = (idx >> 10) & 7, tile = idx >> 13;
        int n = ((idx >> 6) & 15) * 16 + (lane & 15);
        unsigned short* d = wp + W2P + idx * 8;
#pragma unroll
        for (int r = 0; r < 8; ++r)
            d[r] = f2bf(w2[(tile * 256 + kt * 32 + (lane >> 4) * 8 + r) * 256 + n]);
    } else if (tid < 295424) {               // wl: [8][64][8], n<3 valid else 0
        int idx = tid - 294912;
        int lane = idx & 63, kt = idx >> 6;
        int n = lane & 15;
        unsigned short* d = wp + WLP + idx * 8;
#pragma unroll
        for (int r = 0; r < 8; ++r) {
            int k = kt * 32 + (lane >> 4) * 8 + r;
            d[r] = (n < 3) ? f2bf(wl[k * 3 + n]) : (unsigned short)0;
        }
    }
}

__global__ __launch_bounds__(1024, 4)
void loe_mfma(const unsigned short* __restrict__ wpk,
              const float* __restrict__ b0, const float* __restrict__ b1,
              const float* __restrict__ b2, const float* __restrict__ bl,
              float* __restrict__ out)
{
    __shared__ __align__(16) char hb[131072];

    const int t = threadIdx.x;
    const int w = t >> 6, lane = t & 63;
    const int l15 = lane & 15, l4 = lane >> 4;
    const int bx = blockIdx.x, by = blockIdx.y;   // 32 x 32 blocks of 16x16 px

    // ---------- posenc -> rows s1 (ord1), pitch 160B, features [0,54)+pad ----
    {
        int s = t >> 2, part = t & 3;
        int di = ((s >> 7) & 1) * 8 + ((s >> 5) & 1) * 4 + ((s >> 4) & 1) * 2 + ((s >> 1) & 1);
        int dj = ((s >> 6) & 1) * 8 + ((s >> 3) & 1) * 4 + ((s >> 2) & 1) * 2 + (s & 1);
        float xi = (float)(by * 16 + di) * (1.f / 256.f) - 1.f;
        float xj = (float)(bx * 16 + dj) * (1.f / 256.f) - 1.f;
        char* row = hb + s * 160;
        if (part == 3) {
            *(unsigned*)row = (unsigned)f2bf(xi) | ((unsigned)f2bf(xj) << 16);
#pragma unroll
            for (int b = 108; b < 128; b += 4) *(unsigned*)(row + b) = 0u;  // pad 54..63
        }
#pragma unroll
        for (int f = part; f < 13; f += 4) {
            float sc = (float)(1 << f) * 0.5f;          // 2^(f-1), exact
            float ri = xi * sc, rj = xj * sc;           // revolutions
            ri -= floorf(ri); rj -= floorf(rj);         // fract -> [0,1)
            float si = hwsin(ri), ci = hwcos(ri);
            float sj = hwsin(rj), cj = hwcos(rj);
            *(unsigned*)(row + 4 + 8 * f) = (unsigned)f2bf(si) | ((unsigned)f2bf(ci) << 16);
            *(unsigned*)(row + 8 + 8 * f) = (unsigned)f2bf(sj) | ((unsigned)f2bf(cj) << 16);
        }
    }
    __syncthreads();

    // ---------- layer 0: posenc (ord1, K=64) -> main (ord1) ------------------
    {
        const int mg = w >> 2, ng = w & 3;
        const int tile0 = ((by >> 1) & 3) * 4 + ((bx >> 1) & 3);
        const unsigned short* wt = wpk + W0P + tile0 * 16384;
        f32x4 acc[4][4];
#pragma unroll
        for (int m = 0; m < 4; ++m)
#pragma unroll
            for (int n = 0; n < 4; ++n) acc[m][n] = (f32x4)0.f;
#pragma unroll
        for (int kt = 0; kt < 2; ++kt) {
            bf16x8 hf[4];
#pragma unroll
            for (int m = 0; m < 4; ++m) {
                int s = (mg * 4 + m) * 16 + l15;
                hf[m] = *(const bf16x8*)(hb + s * 160 + kt * 64 + l4 * 16);
            }
#pragma unroll
            for (int n = 0; n < 4; ++n) {
                bf16x8 wf = *(const bf16x8*)(wt + (kt * 16 + ng * 4 + n) * 512 + lane * 8);
#pragma unroll
                for (int m = 0; m < 4; ++m)
                    acc[m][n] = __builtin_amdgcn_mfma_f32_16x16x32_bf16(wf, hf[m], acc[m][n], 0, 0, 0);
            }
        }
        __syncthreads();
#pragma unroll
        for (int n = 0; n < 4; ++n) {
            int nt = ng * 4 + n;
            f32x4 bv = *(const f32x4*)(b0 + nt * 16 + l4 * 4);
#pragma unroll
            for (int m = 0; m < 4; ++m) {
                int s = (mg * 4 + m) * 16 + l15;
                uint2 pk;
                pk.x = cvtpk(leaky(acc[m][n][0] + bv[0]), leaky(acc[m][n][1] + bv[1]));
                pk.y = cvtpk(leaky(acc[m][n][2] + bv[2]), leaky(acc[m][n][3] + bv[3]));
                *(uint2*)(hb + rowaddr(s, nt * 32 + l4 * 8)) = pk;
            }
        }
    }
    __syncthreads();

    // ---------- layer 1: main (ord1) -> main (ord2) --------------------------
    {
        const int g = w >> 2, ng = w & 3;
        const int tile1 = ((2 * by + (g >> 1)) & 3) * 4 + ((2 * bx + (g & 1)) & 3);
        const unsigned short* wt = wpk + W1P + tile1 * 65536;
        f32x4 acc[4][4];
#pragma unroll
        for (int m = 0; m < 4; ++m)
#pragma unroll
            for (int n = 0; n < 4; ++n) acc[m][n] = (f32x4)0.f;
#pragma unroll
        for (int kt = 0; kt < 8; ++kt) {
            bf16x8 hf[4];
#pragma unroll
            for (int m = 0; m < 4; ++m) {
                int s = (g * 4 + m) * 16 + l15;
                hf[m] = *(const bf16x8*)(hb + rowaddr(s, kt * 64 + l4 * 16));
            }
#pragma unroll
            for (int n = 0; n < 4; ++n) {
                bf16x8 wf = *(const bf16x8*)(wt + (kt * 16 + ng * 4 + n) * 512 + lane * 8);
#pragma unroll
                for (int m = 0; m < 4; ++m)
                    acc[m][n] = __builtin_amdgcn_mfma_f32_16x16x32_bf16(wf, hf[m], acc[m][n], 0, 0, 0);
            }
        }
        __syncthreads();
#pragma unroll
        for (int n = 0; n < 4; ++n) {
            int nt = ng * 4 + n;
            f32x4 bv = *(const f32x4*)(b1 + nt * 16 + l4 * 4);
#pragma unroll
            for (int m = 0; m < 4; ++m) {
                int P1 = g * 4 + m;
                int s2 = ((((P1 & 3) << 2) | (l15 >> 2)) << 4) | ((P1 >> 2) << 2) | (l15 & 3);
                uint2 pk;
                pk.x = cvtpk(leaky(acc[m][n][0] + bv[0]), leaky(acc[m][n][1] + bv[1]));
                pk.y = cvtpk(leaky(acc[m][n][2] + bv[2]), leaky(acc[m][n][3] + bv[3]));
                *(uint2*)(hb + rowaddr(s2, nt * 32 + l4 * 8)) = pk;
            }
        }
    }
    __syncthreads();

    // ---------- layer 2: main (ord2) -> main (ord2); tile = group = wave -----
    {
        const unsigned short* wt = wpk + W2P + w * 65536;
        f32x4 acc[16];
#pragma unroll
        for (int n = 0; n < 16; ++n) acc[n] = (f32x4)0.f;
        const int s = w * 16 + l15;
#pragma unroll
        for (int kt = 0; kt < 8; ++kt) {
            bf16x8 hf = *(const bf16x8*)(hb + rowaddr(s, kt * 64 + l4 * 16));
#pragma unroll
            for (int n = 0; n < 16; ++n) {
                bf16x8 wf = *(const bf16x8*)(wt + (kt * 16 + n) * 512 + lane * 8);
                acc[n] = __builtin_amdgcn_mfma_f32_16x16x32_bf16(wf, hf, acc[n], 0, 0, 0);
            }
        }
        __syncthreads();
#pragma unroll
        for (int n = 0; n < 16; ++n) {
            f32x4 bv = *(const f32x4*)(b2 + n * 16 + l4 * 4);
            uint2 pk;
            pk.x = cvtpk(leaky(acc[n][0] + bv[0]), leaky(acc[n][1] + bv[1]));
            pk.y = cvtpk(leaky(acc[n][2] + bv[2]), leaky(acc[n][3] + bv[3]));
            *(uint2*)(hb + rowaddr(s, n * 32 + l4 * 8)) = pk;
        }
    }
    // no barrier: head wave w reads only rows w*16.. which wave w itself wrote

    // ---------- head: MFMA with packed w_last; stage; coalesced out ----------
    {
        f32x4 acc = (f32x4)0.f;
        const int s = w * 16 + l15;
#pragma unroll
        for (int kt = 0; kt < 8; ++kt) {
            bf16x8 hf = *(const bf16x8*)(hb + rowaddr(s, kt * 64 + l4 * 16));
            bf16x8 wf = *(const bf16x8*)(wpk + WLP + kt * 512 + lane * 8);
            acc = __builtin_amdgcn_mfma_f32_16x16x32_bf16(wf, hf, acc, 0, 0, 0);
        }
        __syncthreads();   // all head reads done before stage region overwrite
        if (l4 == 0) {
            int q = l15, P2 = w;
            int di = ((q >> 3) & 1) * 8 + ((P2 >> 3) & 1) * 4 + ((P2 >> 2) & 1) * 2 + ((q >> 1) & 1);
            int dj = ((q >> 2) & 1) * 8 + ((P2 >> 1) & 1) * 4 + (P2 & 1) * 2 + (q & 1);
            float* st = (float*)hb + (di * 16 + dj) * 3;
            st[0] = acc[0] + bl[0];
            st[1] = acc[1] + bl[1];
            st[2] = acc[2] + bl[2];
        }
    }
    __syncthreads();
    if (t < 768) {
        int row = t / 48, c = t - row * 48;
        out[(by * 16 + row) * 1536 + bx * 48 + c] = ((const float*)hb)[t];
    }
}

extern "C" void kernel_launch(void* const* d_in, const int* in_sizes, int n_in,
                              void* d_out, int out_size, void* d_ws, size_t ws_size,
                              hipStream_t stream) {
    // inputs: x, labels, w0, b0, w1, b1, w2, b2, w_last, b_last
    const float* w0 = (const float*)d_in[2];
    const float* b0 = (const float*)d_in[3];
    const float* w1 = (const float*)d_in[4];
    const float* b1 = (const float*)d_in[5];
    const float* w2 = (const float*)d_in[6];
    const float* b2 = (const float*)d_in[7];
    const float* wl = (const float*)d_in[8];
    const float* bl = (const float*)d_in[9];
    unsigned short* wpk = (unsigned short*)d_ws;     // ~4.73 MiB of ws
    float* out = (float*)d_out;

    pack_w<<<1154, 256, 0, stream>>>(w0, w1, w2, wl, wpk);
    dim3 grid(32, 32);
    loe_mfma<<<grid, 1024, 0, stream>>>(wpk, b0, b1, b2, bl, out);
}

// Round 7
// 223.846 us; speedup vs baseline: 1.4391x; 1.4391x over previous
//
#include <hip/hip_runtime.h>
#include <math.h>

// LoE tiled MLP — bf16 MFMA v5: spill fix. (Resubmission — round 6 bench never
// acquired a GPU; no changes vs round 5.)
// v4 was 100% scratch-spill-bound: 1024-thr blocks (4 waves/SIMD) cap unified
// regs at 128/wave; live set exceeded it -> 256 MB/dispatch HBM spill traffic.
// v5: 512-thr blocks (8 waves, 2/SIMD, cap 256 regs), each wave does 2x work:
//   L0/L1: wave w -> Mtile group g=w>>1 (4 Mtiles), Ntile half=w&1 (8 Ntiles),
//          acc[4][8] (128 regs, OK at 2 waves/EU).
//   L2/head: wave w -> idx2 groups {2w, 2w+1} SEQUENTIALLY, acc[16] each;
//          no barrier (wave reads/writes only its own 16 rows per group).
// pack_w rewritten: register-transpose, coalesced 1KB reads / 16B frag stores.
//
// Carried over from v3/v4 (verified):
//   ord1 row s1 = [d3 e3 d2 d1 | e2 e1 d0 e0]; ord2 s2 = [d2 d1 e2 e1 | d3 e3 d0 e0]
//   weights packed as A-role fragments [tile][kt][nt][lane][8]; h = B operand
//   -> mfma(w,h) = D^T: lane holds 4 consecutive features of one pixel
//   -> epilogue = 2 cvt_pk + 1 ds_write_b64; row perms free.
//   activation rows 512B, phys = s*512 + ((off + (s&7)*64 + ((s>>3)&1)*32)&511).
//   posenc: sin(pi*2^f*x) = v_sin_f32(fract(x*2^(f-1))).

typedef __attribute__((ext_vector_type(8))) short bf16x8;
typedef __attribute__((ext_vector_type(4))) float f32x4;

#define W0P 0
#define W1P 262144
#define W2P 1310720
#define WLP 2359296

__device__ __forceinline__ unsigned short f2bf(float f){
    unsigned b = __float_as_uint(f);
    return (unsigned short)((b + 0x7FFFu + ((b >> 16) & 1u)) >> 16);
}
__device__ __forceinline__ unsigned cvtpk(float lo, float hi){
    unsigned r;
    asm("v_cvt_pk_bf16_f32 %0, %1, %2" : "=v"(r) : "v"(lo), "v"(hi));
    return r;
}
__device__ __forceinline__ float hwsin(float r){
    float d; asm("v_sin_f32 %0, %1" : "=v"(d) : "v"(r)); return d;
}
__device__ __forceinline__ float hwcos(float r){
    float d; asm("v_cos_f32 %0, %1" : "=v"(d) : "v"(r)); return d;
}
__device__ __forceinline__ float leaky(float v){ return fmaxf(v, 0.2f * v); }
__device__ __forceinline__ int rowaddr(int s, int off){
    return s * 512 + ((off + (s & 7) * 64 + ((s >> 3) & 1) * 32) & 511);
}

// -------- pack_w v2: register-transpose, coalesced both sides --------------
// Block b handles one (matrix, tile, kt) chunk of 32 k-rows x 256 cols.
// Thread t owns column n=t: 32 coalesced 1KB row-reads, pack to 16 uints,
// write 4 fragments (16B each, coalesced within 16-lane groups).
__global__ __launch_bounds__(256)
void pack_w(const float* __restrict__ w0, const float* __restrict__ w1,
            const float* __restrict__ w2, const float* __restrict__ wl,
            unsigned short* __restrict__ wp)
{
    const int b = blockIdx.x, t = threadIdx.x;
    if (b < 288) {
        const float* src; unsigned short* dst; int kmax, kt;
        if (b < 32)       { int tile = b >> 1;  kt = b & 1;  src = w0 + tile * (54 * 256);  dst = wp + W0P + b * 8192;          kmax = 54;  }
        else if (b < 160) { int ib = b - 32;    kt = ib & 7; src = w1 + (ib >> 3) * 65536;  dst = wp + W1P + ib * 8192;         kmax = 256; }
        else              { int ib = b - 160;   kt = ib & 7; src = w2 + (ib >> 3) * 65536;  dst = wp + W2P + ib * 8192;         kmax = 256; }
        unsigned u[16];
#pragma unroll
        for (int i2 = 0; i2 < 16; ++i2) {
            int k0 = kt * 32 + i2 * 2;
            float v0 = (k0     < kmax) ? src[k0 * 256 + t]       : 0.f;
            float v1 = (k0 + 1 < kmax) ? src[(k0 + 1) * 256 + t] : 0.f;
            u[i2] = cvtpk(v0, v1);              // lo short = k0, hi short = k0+1
        }
        unsigned short* dcol = dst + (((t >> 4) << 6) + (t & 15)) * 8;
#pragma unroll
        for (int q = 0; q < 4; ++q) {           // q = lane>>4 of the fragment
            uint4 val;
            val.x = u[q * 4]; val.y = u[q * 4 + 1]; val.z = u[q * 4 + 2]; val.w = u[q * 4 + 3];
            *(uint4*)(dcol + (q << 4) * 8) = val;
        }
    } else {
        // w_last: [8 kt][64 lane][8]; cols n<3 valid else 0
        for (int idx = t; idx < 512; idx += 256) {
            int kt = idx >> 6, lane = idx & 63, n = lane & 15;
            unsigned u[4];
#pragma unroll
            for (int r2 = 0; r2 < 4; ++r2) {
                int k = kt * 32 + (lane >> 4) * 8 + r2 * 2;
                float v0 = (n < 3) ? wl[k * 3 + n]       : 0.f;
                float v1 = (n < 3) ? wl[(k + 1) * 3 + n] : 0.f;
                u[r2] = cvtpk(v0, v1);
            }
            uint4 val; val.x = u[0]; val.y = u[1]; val.z = u[2]; val.w = u[3];
            *(uint4*)(wp + WLP + idx * 8) = val;
        }
    }
}

__global__ __launch_bounds__(512, 2)
void loe_mfma(const unsigned short* __restrict__ wpk,
              const float* __restrict__ b0, const float* __restrict__ b1,
              const float* __restrict__ b2, const float* __restrict__ bl,
              float* __restrict__ out)
{
    __shared__ __align__(16) char hb[131072];

    const int t = threadIdx.x;
    const int w = t >> 6, lane = t & 63;
    const int l15 = lane & 15, l4 = lane >> 4;
    const int g = w >> 1, half = w & 1;
    const int bx = blockIdx.x, by = blockIdx.y;   // 32 x 32 blocks of 16x16 px

    // ---------- posenc -> rows s1 (ord1), pitch 160B ------------------------
    {
        int s = t >> 1, part = t & 1;
        int di = ((s >> 7) & 1) * 8 + ((s >> 5) & 1) * 4 + ((s >> 4) & 1) * 2 + ((s >> 1) & 1);
        int dj = ((s >> 6) & 1) * 8 + ((s >> 3) & 1) * 4 + ((s >> 2) & 1) * 2 + (s & 1);
        float xi = (float)(by * 16 + di) * (1.f / 256.f) - 1.f;
        float xj = (float)(bx * 16 + dj) * (1.f / 256.f) - 1.f;
        char* row = hb + s * 160;
        if (part) {
            *(unsigned*)row = (unsigned)f2bf(xi) | ((unsigned)f2bf(xj) << 16);
#pragma unroll
            for (int bpad = 108; bpad < 128; bpad += 4) *(unsigned*)(row + bpad) = 0u;
        }
#pragma unroll
        for (int f = part; f < 13; f += 2) {
            float sc = (float)(1 << f) * 0.5f;          // 2^(f-1), exact
            float ri = xi * sc, rj = xj * sc;           // revolutions
            ri -= floorf(ri); rj -= floorf(rj);
            float si = hwsin(ri), ci = hwcos(ri);
            float sj = hwsin(rj), cj = hwcos(rj);
            *(unsigned*)(row + 4 + 8 * f) = (unsigned)f2bf(si) | ((unsigned)f2bf(ci) << 16);
            *(unsigned*)(row + 8 + 8 * f) = (unsigned)f2bf(sj) | ((unsigned)f2bf(cj) << 16);
        }
    }
    __syncthreads();

    // ---------- layer 0: posenc (ord1, K=64) -> main (ord1) ------------------
    {
        const int tile0 = ((by >> 1) & 3) * 4 + ((bx >> 1) & 3);
        const unsigned short* wt = wpk + W0P + tile0 * 16384;
        f32x4 acc[4][8];
#pragma unroll
        for (int m = 0; m < 4; ++m)
#pragma unroll
            for (int n = 0; n < 8; ++n) acc[m][n] = (f32x4)0.f;
#pragma unroll
        for (int kt = 0; kt < 2; ++kt) {
            bf16x8 hf[4];
#pragma unroll
            for (int m = 0; m < 4; ++m) {
                int s = (g * 4 + m) * 16 + l15;
                hf[m] = *(const bf16x8*)(hb + s * 160 + kt * 64 + l4 * 16);
            }
#pragma unroll
            for (int n = 0; n < 8; ++n) {
                bf16x8 wf = *(const bf16x8*)(wt + (kt * 16 + half * 8 + n) * 512 + lane * 8);
#pragma unroll
                for (int m = 0; m < 4; ++m)
                    acc[m][n] = __builtin_amdgcn_mfma_f32_16x16x32_bf16(wf, hf[m], acc[m][n], 0, 0, 0);
            }
        }
        __syncthreads();
#pragma unroll
        for (int n = 0; n < 8; ++n) {
            int nt = half * 8 + n;
            f32x4 bv = *(const f32x4*)(b0 + nt * 16 + l4 * 4);
#pragma unroll
            for (int m = 0; m < 4; ++m) {
                int s = (g * 4 + m) * 16 + l15;
                uint2 pk;
                pk.x = cvtpk(leaky(acc[m][n][0] + bv[0]), leaky(acc[m][n][1] + bv[1]));
                pk.y = cvtpk(leaky(acc[m][n][2] + bv[2]), leaky(acc[m][n][3] + bv[3]));
                *(uint2*)(hb + rowaddr(s, nt * 32 + l4 * 8)) = pk;
            }
        }
    }
    __syncthreads();

    // ---------- layer 1: main (ord1) -> main (ord2) --------------------------
    {
        const int tile1 = ((2 * by + (g >> 1)) & 3) * 4 + ((2 * bx + (g & 1)) & 3);
        const unsigned short* wt = wpk + W1P + tile1 * 65536;
        f32x4 acc[4][8];
#pragma unroll
        for (int m = 0; m < 4; ++m)
#pragma unroll
            for (int n = 0; n < 8; ++n) acc[m][n] = (f32x4)0.f;
#pragma unroll
        for (int kt = 0; kt < 8; ++kt) {
            bf16x8 hf[4];
#pragma unroll
            for (int m = 0; m < 4; ++m) {
                int s = (g * 4 + m) * 16 + l15;
                hf[m] = *(const bf16x8*)(hb + rowaddr(s, kt * 64 + l4 * 16));
            }
#pragma unroll
            for (int n = 0; n < 8; ++n) {
                bf16x8 wf = *(const bf16x8*)(wt + (kt * 16 + half * 8 + n) * 512 + lane * 8);
#pragma unroll
                for (int m = 0; m < 4; ++m)
                    acc[m][n] = __builtin_amdgcn_mfma_f32_16x16x32_bf16(wf, hf[m], acc[m][n], 0, 0, 0);
            }
        }
        __syncthreads();
#pragma unroll
        for (int n = 0; n < 8; ++n) {
            int nt = half * 8 + n;
            f32x4 bv = *(const f32x4*)(b1 + nt * 16 + l4 * 4);
#pragma unroll
            for (int m = 0; m < 4; ++m) {
                int P1 = g * 4 + m;
                int s2 = ((((P1 & 3) << 2) | (l15 >> 2)) << 4) | ((P1 >> 2) << 2) | (l15 & 3);
                uint2 pk;
                pk.x = cvtpk(leaky(acc[m][n][0] + bv[0]), leaky(acc[m][n][1] + bv[1]));
                pk.y = cvtpk(leaky(acc[m][n][2] + bv[2]), leaky(acc[m][n][3] + bv[3]));
                *(uint2*)(hb + rowaddr(s2, nt * 32 + l4 * 8)) = pk;
            }
        }
    }
    __syncthreads();

    // ---------- layer 2: main (ord2) in-place; wave w -> groups 2w, 2w+1 -----
#pragma unroll 1
    for (int gg = 0; gg < 2; ++gg) {
        const int grp = w * 2 + gg;
        const unsigned short* wt = wpk + W2P + grp * 65536;
        const int s = grp * 16 + l15;
        f32x4 acc[16];
#pragma unroll
        for (int n = 0; n < 16; ++n) acc[n] = (f32x4)0.f;
#pragma unroll
        for (int kt = 0; kt < 8; ++kt) {
            bf16x8 hf = *(const bf16x8*)(hb + rowaddr(s, kt * 64 + l4 * 16));
#pragma unroll
            for (int n = 0; n < 16; ++n) {
                bf16x8 wf = *(const bf16x8*)(wt + (kt * 16 + n) * 512 + lane * 8);
                acc[n] = __builtin_amdgcn_mfma_f32_16x16x32_bf16(wf, hf, acc[n], 0, 0, 0);
            }
        }
        // wave reads/writes only its own rows -> no barrier needed
#pragma unroll
        for (int n = 0; n < 16; ++n) {
            f32x4 bv = *(const f32x4*)(b2 + n * 16 + l4 * 4);
            uint2 pk;
            pk.x = cvtpk(leaky(acc[n][0] + bv[0]), leaky(acc[n][1] + bv[1]));
            pk.y = cvtpk(leaky(acc[n][2] + bv[2]), leaky(acc[n][3] + bv[3]));
            *(uint2*)(hb + rowaddr(s, n * 32 + l4 * 8)) = pk;
        }
    }

    // ---------- head: groups 2w, 2w+1 (rows this wave wrote in L2) -----------
    {
        f32x4 ha[2];
#pragma unroll
        for (int gg = 0; gg < 2; ++gg) {
            const int grp = w * 2 + gg;
            const int s = grp * 16 + l15;
            ha[gg] = (f32x4)0.f;
#pragma unroll
            for (int kt = 0; kt < 8; ++kt) {
                bf16x8 hf = *(const bf16x8*)(hb + rowaddr(s, kt * 64 + l4 * 16));
                bf16x8 wf = *(const bf16x8*)(wpk + WLP + kt * 512 + lane * 8);
                ha[gg] = __builtin_amdgcn_mfma_f32_16x16x32_bf16(wf, hf, ha[gg], 0, 0, 0);
            }
        }
        __syncthreads();   // all head reads done before stage region overwrite
        if (l4 == 0) {
#pragma unroll
            for (int gg = 0; gg < 2; ++gg) {
                int q = l15, P2 = w * 2 + gg;
                int di = ((q >> 3) & 1) * 8 + ((P2 >> 3) & 1) * 4 + ((P2 >> 2) & 1) * 2 + ((q >> 1) & 1);
                int dj = ((q >> 2) & 1) * 8 + ((P2 >> 1) & 1) * 4 + (P2 & 1) * 2 + (q & 1);
                float* st = (float*)hb + (di * 16 + dj) * 3;
                st[0] = ha[gg][0] + bl[0];
                st[1] = ha[gg][1] + bl[1];
                st[2] = ha[gg][2] + bl[2];
            }
        }
    }
    __syncthreads();
#pragma unroll
    for (int idx = t; idx < 768; idx += 512) {
        int row = idx / 48, c = idx - row * 48;
        out[(by * 16 + row) * 1536 + bx * 48 + c] = ((const float*)hb)[idx];
    }
}

extern "C" void kernel_launch(void* const* d_in, const int* in_sizes, int n_in,
                              void* d_out, int out_size, void* d_ws, size_t ws_size,
                              hipStream_t stream) {
    // inputs: x, labels, w0, b0, w1, b1, w2, b2, w_last, b_last
    const float* w0 = (const float*)d_in[2];
    const float* b0 = (const float*)d_in[3];
    const float* w1 = (const float*)d_in[4];
    const float* b1 = (const float*)d_in[5];
    const float* w2 = (const float*)d_in[6];
    const float* b2 = (const float*)d_in[7];
    const float* wl = (const float*)d_in[8];
    const float* bl = (const float*)d_in[9];
    unsigned short* wpk = (unsigned short*)d_ws;     // ~4.73 MiB of ws
    float* out = (float*)d_out;

    pack_w<<<289, 256, 0, stream>>>(w0, w1, w2, wl, wpk);
    dim3 grid(32, 32);
    loe_mfma<<<grid, 512, 0, stream>>>(wpk, b0, b1, b2, bl, out);
}